// Round 1
// 810.944 us; speedup vs baseline: 1.0534x; 1.0534x over previous
//
#include <hip/hip_runtime.h>
#include <hip/hip_bf16.h>
#include <stdint.h>

#define Bn 16
#define Nn 8192
#define Dn 1024
#define Hn 256

typedef __attribute__((ext_vector_type(8))) short bf16x8;
typedef __attribute__((ext_vector_type(4))) float f32x4;

__device__ __forceinline__ short f2bf(float f) {
    __hip_bfloat16 h = __float2bfloat16(f);   // hw RNE cvt (compiler packs to v_cvt_pk_bf16_f32)
    return *reinterpret_cast<short*>(&h);
}

// fast tanh: 1 - 2/(1+e^{2x}); exact at +/-inf, ~1e-6 abs err
__device__ __forceinline__ float tanh_fast(float x) {
    float e = __expf(2.0f * x);
    return 1.0f - __fdividef(2.0f, 1.0f + e);
}

// ---------------- W1 fp32 -> bf16, panel-major + XOR-swizzled ----------------
// Layout: 16 panels (k-panel p = k/64), each panel 256 rows x 64 k bf16 = 32768 B.
// Within panel, 16B chunk (h, c8) stored at byte  h*128 + ((c8 ^ (h&7))<<4).
// k_scores stages a panel LINEARLY with global_load_lds; the ds_read applies the
// same XOR -> conflict-free (rows spread over all 32 banks per 8-row stripe).
__global__ __launch_bounds__(256) void k_cvt_w1(const float* __restrict__ W1,
                                                short* __restrict__ w1s) {
    int i   = blockIdx.x * 256 + threadIdx.x;  // one thread per 8 consecutive k
    int h   = i >> 7;                          // row 0..255
    int kk8 = i & 127;                         // 8-elem chunk along k (0..127)
    int p   = kk8 >> 3;                        // panel 0..15
    int c8  = kk8 & 7;                         // chunk within panel 0..7
    const float* src = W1 + h * Dn + kk8 * 8;
    bf16x8 pk;
#pragma unroll
    for (int j = 0; j < 8; ++j) pk[j] = f2bf(src[j]);
    char* dst = (char*)w1s + p * 32768 + h * 128 + ((c8 ^ (h & 7)) << 4);
    *(bf16x8*)dst = pk;
}

// ---------------- scores GEMM: X[131072,1024] x W1^T -> tanh -> dot W2 --------
// Block: 128 rows x 256 cols (all H), 8 waves (2x4), wave tile 64x64, BK=64.
// W1 panel staged via global_load_lds (16B); X staged reg-side with hw cvt.
#define XSTR 72   // padded X row stride (bf16 elems): 144 B -> 2-way (free) on frag reads

__global__ __launch_bounds__(512) void k_scores(const float* __restrict__ X,
                                                const short* __restrict__ w1s,
                                                const float* __restrict__ W2,
                                                float* __restrict__ scores) {
    __shared__ short xa[128 * XSTR];   // 18432 B
    __shared__ short wb[256 * 64];     // 32768 B (swizzled panel, linear image)
    __shared__ float sc[128];

    const int tid  = threadIdx.x;
    const int wave = tid >> 6;
    const int lane = tid & 63;
    const int quad = lane >> 4;
    const int l16  = lane & 15;
    const int wr   = wave >> 2;        // 0..1  (row half)
    const int wc   = wave & 3;         // 0..3  (col quarter)

    const long row0 = (long)blockIdx.x * 128;
    const float* xbase = X + row0 * Dn;

    // X staging map: thread t -> row t>>2, k-offset (t&3)*16 (16 fp32 = 4 float4)
    const int srow = tid >> 2;
    const int sk   = (tid & 3) << 4;

    f32x4 acc[4][4];
#pragma unroll
    for (int mi = 0; mi < 4; ++mi)
#pragma unroll
        for (int ni = 0; ni < 4; ++ni)
            acc[mi][ni] = (f32x4){0.f, 0.f, 0.f, 0.f};

    float w2v[4];
#pragma unroll
    for (int ni = 0; ni < 4; ++ni) w2v[ni] = W2[wc * 64 + ni * 16 + l16];

    for (int k0 = 0; k0 < Dn; k0 += 64) {
        // ---- stage X tile (128x64) fp32 -> bf16 in registers ----
        {
            const float* src = xbase + (long)srow * Dn + k0 + sk;
            float4 f0 = *(const float4*)(src);
            float4 f1 = *(const float4*)(src + 4);
            float4 f2 = *(const float4*)(src + 8);
            float4 f3 = *(const float4*)(src + 12);
            bf16x8 p0, p1;
            p0[0] = f2bf(f0.x); p0[1] = f2bf(f0.y); p0[2] = f2bf(f0.z); p0[3] = f2bf(f0.w);
            p0[4] = f2bf(f1.x); p0[5] = f2bf(f1.y); p0[6] = f2bf(f1.z); p0[7] = f2bf(f1.w);
            p1[0] = f2bf(f2.x); p1[1] = f2bf(f2.y); p1[2] = f2bf(f2.z); p1[3] = f2bf(f2.w);
            p1[4] = f2bf(f3.x); p1[5] = f2bf(f3.y); p1[6] = f2bf(f3.z); p1[7] = f2bf(f3.w);
            *(bf16x8*)(&xa[srow * XSTR + sk]) = p0;
            *(bf16x8*)(&xa[srow * XSTR + sk + 8]) = p1;
        }
        // ---- stage W1 panel (256x64 bf16 = 32 KB) via global_load_lds x4 ----
        {
            const char* wsrc = (const char*)w1s + ((long)k0 << 9);  // k0/64*32768
            char* wdst = (char*)wb;
#pragma unroll
            for (int j = 0; j < 4; ++j)
                __builtin_amdgcn_global_load_lds(
                    (const __attribute__((address_space(1))) unsigned int*)(wsrc + j * 8192 + tid * 16),
                    (__attribute__((address_space(3))) unsigned int*)(wdst + j * 8192 + tid * 16),
                    16, 0, 0);
        }
        __syncthreads();

#pragma unroll
        for (int ks = 0; ks < 2; ++ks) {
            bf16x8 af[4], bq[4];
#pragma unroll
            for (int mi = 0; mi < 4; ++mi)
                af[mi] = *(const bf16x8*)(&xa[(wr * 64 + mi * 16 + l16) * XSTR + ks * 32 + quad * 8]);
#pragma unroll
            for (int ni = 0; ni < 4; ++ni) {
                int rw    = wc * 64 + ni * 16 + l16;
                int byteo = (rw * 128 + ks * 64 + quad * 16) ^ ((rw & 7) << 4);
                bq[ni] = *(const bf16x8*)((const char*)wb + byteo);
            }
#pragma unroll
            for (int mi = 0; mi < 4; ++mi)
#pragma unroll
                for (int ni = 0; ni < 4; ++ni)
                    acc[mi][ni] = __builtin_amdgcn_mfma_f32_16x16x32_bf16(af[mi], bq[ni], acc[mi][ni], 0, 0, 0);
        }
        __syncthreads();
    }

    // ---- epilogue: score[row] = sum_h W2[h]*tanh(C[row,h]) ----
    // C/D layout: col = l16 (+ni*16 + wc*64), row = quad*4 + r (+mi*16 + wr*64)
    if (tid < 128) sc[tid] = 0.f;
    __syncthreads();

#pragma unroll
    for (int mi = 0; mi < 4; ++mi) {
#pragma unroll
        for (int r = 0; r < 4; ++r) {
            float p = 0.f;
#pragma unroll
            for (int ni = 0; ni < 4; ++ni)
                p += w2v[ni] * tanh_fast(acc[mi][ni][r]);
            p += __shfl_xor(p, 1);
            p += __shfl_xor(p, 2);
            p += __shfl_xor(p, 4);
            p += __shfl_xor(p, 8);
            if (l16 == 0) atomicAdd(&sc[wr * 64 + mi * 16 + quad * 4 + r], p);
        }
    }
    __syncthreads();
    if (tid < 128) scores[row0 + tid] = sc[tid];
}

// ---------------- softmax over N per batch: 1024 thr, 1 read pass ----------------
__global__ __launch_bounds__(1024) void k_softmax(const float* __restrict__ scores,
                                                  float* __restrict__ attn) {
    const int b   = blockIdx.x;
    const int tid = threadIdx.x;
    const float* s = scores + b * Nn;
    __shared__ float redm[16];
    __shared__ float reds[16];

    float4 v0 = ((const float4*)s)[tid * 2];
    float4 v1 = ((const float4*)s)[tid * 2 + 1];

    float m = fmaxf(fmaxf(fmaxf(v0.x, v0.y), fmaxf(v0.z, v0.w)),
                    fmaxf(fmaxf(v1.x, v1.y), fmaxf(v1.z, v1.w)));
#pragma unroll
    for (int o = 32; o >= 1; o >>= 1) m = fmaxf(m, __shfl_xor(m, o));
    if ((tid & 63) == 0) redm[tid >> 6] = m;
    __syncthreads();
    m = redm[0];
#pragma unroll
    for (int i = 1; i < 16; ++i) m = fmaxf(m, redm[i]);

    float e[8];
    e[0] = __expf(v0.x - m); e[1] = __expf(v0.y - m);
    e[2] = __expf(v0.z - m); e[3] = __expf(v0.w - m);
    e[4] = __expf(v1.x - m); e[5] = __expf(v1.y - m);
    e[6] = __expf(v1.z - m); e[7] = __expf(v1.w - m);
    float sum = ((e[0] + e[1]) + (e[2] + e[3])) + ((e[4] + e[5]) + (e[6] + e[7]));
#pragma unroll
    for (int o = 32; o >= 1; o >>= 1) sum += __shfl_xor(sum, o);
    if ((tid & 63) == 0) reds[tid >> 6] = sum;
    __syncthreads();
    float tot = 0.f;
#pragma unroll
    for (int i = 0; i < 16; ++i) tot += reds[i];
    const float inv = 1.0f / tot;

    float* a = attn + b * Nn;
    float4 o0 = make_float4(e[0] * inv, e[1] * inv, e[2] * inv, e[3] * inv);
    float4 o1 = make_float4(e[4] * inv, e[5] * inv, e[6] * inv, e[7] * inv);
    ((float4*)a)[tid * 2]     = o0;
    ((float4*)a)[tid * 2 + 1] = o1;
}

// ---------------- pass 2: partials, no atomics, reverse order for L3 tail hits ----
// part[b][c][d] : [16][64][1024] fp32 = 4 MB
__global__ __launch_bounds__(256) void k_wsum(const float* __restrict__ X,
                                              const float* __restrict__ attn,
                                              float* __restrict__ part) {
    const int slot = blockIdx.y * 64 + blockIdx.x;
    const int flat = 1023 - slot;          // earliest blocks take the X tail (hot in L3)
    const int b    = flat >> 6;
    const int c    = flat & 63;
    const int tid  = threadIdx.x;
    __shared__ float a_s[128];
    if (tid < 128) a_s[tid] = attn[b * Nn + c * 128 + tid];
    __syncthreads();

    const float* xp = X + ((long)b * Nn + (long)c * 128) * Dn + tid * 4;
    float4 acc = make_float4(0.f, 0.f, 0.f, 0.f);
#pragma unroll 4
    for (int n = 0; n < 128; ++n) {
        float4 x = *(const float4*)(xp + (long)n * Dn);
        float a = a_s[n];
        acc.x += a * x.x; acc.y += a * x.y; acc.z += a * x.z; acc.w += a * x.w;
    }
    *(float4*)(part + (long)flat * Dn + tid * 4) = acc;
}

// out[b][d] = sum_c part[b][c][d]   (4 MB read, trivial)
__global__ __launch_bounds__(256) void k_reduce(const float* __restrict__ part,
                                                float* __restrict__ out) {
    int i = blockIdx.x * 256 + threadIdx.x;   // 0..16383
    int b = i >> 10;
    int d = i & 1023;
    const float* p = part + (long)b * 64 * Dn + d;
    float s = 0.f;
#pragma unroll 8
    for (int c = 0; c < 64; ++c) s += p[c * Dn];
    out[i] = s;
}

extern "C" void kernel_launch(void* const* d_in, const int* in_sizes, int n_in,
                              void* d_out, int out_size, void* d_ws, size_t ws_size,
                              hipStream_t stream) {
    (void)in_sizes; (void)n_in; (void)ws_size; (void)out_size;
    const float* X  = (const float*)d_in[0];
    const float* W1 = (const float*)d_in[1];
    const float* W2 = (const float*)d_in[2];
    float* out = (float*)d_out;

    char* ws = (char*)d_ws;
    short* w1s    = (short*)ws;                      // 512 KB (swizzled panels)
    float* scores = (float*)(ws + (1 << 19));        // 512 KB
    float* attn   = (float*)(ws + (2 << 19));        // 512 KB
    float* part   = (float*)(ws + (3 << 19));        // 4 MB

    k_cvt_w1<<<(Hn * Dn) / 8 / 256, 256, 0, stream>>>(W1, w1s);
    k_scores<<<(Bn * Nn) / 128, 512, 0, stream>>>(X, w1s, W2, scores);
    k_softmax<<<Bn, 1024, 0, stream>>>(scores, attn);
    dim3 g(64, Bn);
    k_wsum<<<g, 256, 0, stream>>>(X, attn, part);
    k_reduce<<<64, 256, 0, stream>>>(part, out);
}

// Round 2
// 801.047 us; speedup vs baseline: 1.0664x; 1.0124x over previous
//
#include <hip/hip_runtime.h>
#include <hip/hip_bf16.h>
#include <stdint.h>

#define Bn 16
#define Nn 8192
#define Dn 1024
#define Hn 256

typedef __attribute__((ext_vector_type(8))) short bf16x8;
typedef __attribute__((ext_vector_type(4))) float f32x4;

__device__ __forceinline__ short f2bf(float f) {
    __hip_bfloat16 h = __float2bfloat16(f);   // hw RNE cvt
    return *reinterpret_cast<short*>(&h);
}

// fast tanh: 1 - 2/(1+e^{2x}); exact at +/-inf
__device__ __forceinline__ float tanh_fast(float x) {
    float e = __expf(2.0f * x);
    return 1.0f - __fdividef(2.0f, 1.0f + e);
}

// ---------------- W1 fp32 -> bf16, panel-major + XOR-swizzled ----------------
// 16 panels (k-panel p = k/64), each 256 rows x 64 k bf16 = 32768 B.
// 16B chunk (h, c8) stored at byte h*128 + ((c8 ^ (h&7))<<4). k_scores stages a
// panel LINEARLY via global_load_lds; ds_read applies the same XOR -> conflict-free.
__global__ __launch_bounds__(256) void k_cvt_w1(const float* __restrict__ W1,
                                                short* __restrict__ w1s) {
    int i   = blockIdx.x * 256 + threadIdx.x;
    int h   = i >> 7;
    int kk8 = i & 127;
    int p   = kk8 >> 3;
    int c8  = kk8 & 7;
    const float* src = W1 + h * Dn + kk8 * 8;
    bf16x8 pk;
#pragma unroll
    for (int j = 0; j < 8; ++j) pk[j] = f2bf(src[j]);
    char* dst = (char*)w1s + p * 32768 + h * 128 + ((c8 ^ (h & 7)) << 4);
    *(bf16x8*)dst = pk;
}

// ---------------- fused: scores GEMM -> local softmax -> weighted partial ----
// Block: 128 rows x 256 cols (all H), 8 waves (2x4), wave tile 64x64, BK=64.
// After GEMM+tanh+dot(W2): chunk-local softmax (m_c, p_n, l_c), then re-read
// the block's own 512 KB X chunk (hot in L2/L3) to form partial[c][d].
#define XSTR 72

__global__ __launch_bounds__(512) void k_scores(const float* __restrict__ X,
                                                const short* __restrict__ w1s,
                                                const float* __restrict__ W2,
                                                float2* __restrict__ ml,
                                                float* __restrict__ partial) {
    __shared__ short xa[128 * XSTR];   // 18432 B
    __shared__ short wb[256 * 64];     // 32768 B (swizzled panel image)
    __shared__ float sc[128];
    __shared__ float mred;

    const int tid  = threadIdx.x;
    const int wave = tid >> 6;
    const int lane = tid & 63;
    const int quad = lane >> 4;
    const int l16  = lane & 15;
    const int wr   = wave >> 2;
    const int wc   = wave & 3;

    const long row0 = (long)blockIdx.x * 128;
    const float* xbase = X + row0 * Dn;

    const int srow = tid >> 2;
    const int sk   = (tid & 3) << 4;

    f32x4 acc[4][4];
#pragma unroll
    for (int mi = 0; mi < 4; ++mi)
#pragma unroll
        for (int ni = 0; ni < 4; ++ni)
            acc[mi][ni] = (f32x4){0.f, 0.f, 0.f, 0.f};

    float w2v[4];
#pragma unroll
    for (int ni = 0; ni < 4; ++ni) w2v[ni] = W2[wc * 64 + ni * 16 + l16];

    for (int k0 = 0; k0 < Dn; k0 += 64) {
        // ---- stage X tile (128x64) fp32 -> bf16 in registers ----
        {
            const float* src = xbase + (long)srow * Dn + k0 + sk;
            float4 f0 = *(const float4*)(src);
            float4 f1 = *(const float4*)(src + 4);
            float4 f2 = *(const float4*)(src + 8);
            float4 f3 = *(const float4*)(src + 12);
            bf16x8 p0, p1;
            p0[0] = f2bf(f0.x); p0[1] = f2bf(f0.y); p0[2] = f2bf(f0.z); p0[3] = f2bf(f0.w);
            p0[4] = f2bf(f1.x); p0[5] = f2bf(f1.y); p0[6] = f2bf(f1.z); p0[7] = f2bf(f1.w);
            p1[0] = f2bf(f2.x); p1[1] = f2bf(f2.y); p1[2] = f2bf(f2.z); p1[3] = f2bf(f2.w);
            p1[4] = f2bf(f3.x); p1[5] = f2bf(f3.y); p1[6] = f2bf(f3.z); p1[7] = f2bf(f3.w);
            *(bf16x8*)(&xa[srow * XSTR + sk]) = p0;
            *(bf16x8*)(&xa[srow * XSTR + sk + 8]) = p1;
        }
        // ---- stage W1 panel (256x64 bf16 = 32 KB) via global_load_lds x4 ----
        {
            const char* wsrc = (const char*)w1s + ((long)k0 << 9);
            char* wdst = (char*)wb;
#pragma unroll
            for (int j = 0; j < 4; ++j)
                __builtin_amdgcn_global_load_lds(
                    (const __attribute__((address_space(1))) unsigned int*)(wsrc + j * 8192 + tid * 16),
                    (__attribute__((address_space(3))) unsigned int*)(wdst + j * 8192 + tid * 16),
                    16, 0, 0);
        }
        __syncthreads();

#pragma unroll
        for (int ks = 0; ks < 2; ++ks) {
            bf16x8 af[4], bq[4];
#pragma unroll
            for (int mi = 0; mi < 4; ++mi)
                af[mi] = *(const bf16x8*)(&xa[(wr * 64 + mi * 16 + l16) * XSTR + ks * 32 + quad * 8]);
#pragma unroll
            for (int ni = 0; ni < 4; ++ni) {
                int rw    = wc * 64 + ni * 16 + l16;
                int byteo = (rw * 128 + ks * 64 + quad * 16) ^ ((rw & 7) << 4);
                bq[ni] = *(const bf16x8*)((const char*)wb + byteo);
            }
#pragma unroll
            for (int mi = 0; mi < 4; ++mi)
#pragma unroll
                for (int ni = 0; ni < 4; ++ni)
                    acc[mi][ni] = __builtin_amdgcn_mfma_f32_16x16x32_bf16(af[mi], bq[ni], acc[mi][ni], 0, 0, 0);
        }
        __syncthreads();
    }

    // ---- epilogue: sc[row] = sum_h W2[h]*tanh(C[row,h]) ----
    if (tid < 128) sc[tid] = 0.f;
    __syncthreads();

#pragma unroll
    for (int mi = 0; mi < 4; ++mi) {
#pragma unroll
        for (int r = 0; r < 4; ++r) {
            float p = 0.f;
#pragma unroll
            for (int ni = 0; ni < 4; ++ni)
                p += w2v[ni] * tanh_fast(acc[mi][ni][r]);
            p += __shfl_xor(p, 1);
            p += __shfl_xor(p, 2);
            p += __shfl_xor(p, 4);
            p += __shfl_xor(p, 8);
            if (l16 == 0) atomicAdd(&sc[wr * 64 + mi * 16 + quad * 4 + r], p);
        }
    }
    __syncthreads();

    // ---- chunk-local softmax partial: m_c, p_n = exp(s-m_c), l_c ----
    if (wave == 0) {
        float v = fmaxf(sc[lane], sc[64 + lane]);
#pragma unroll
        for (int o = 32; o >= 1; o >>= 1) v = fmaxf(v, __shfl_xor(v, o));
        if (lane == 0) mred = v;
    }
    __syncthreads();
    const float m_c = mred;
    if (tid < 128) sc[tid] = __expf(sc[tid] - m_c);
    __syncthreads();
    if (wave == 0) {
        float s = sc[lane] + sc[64 + lane];
#pragma unroll
        for (int o = 32; o >= 1; o >>= 1) s += __shfl_xor(s, o);
        if (lane == 0) ml[blockIdx.x] = make_float2(m_c, s);
    }

    // ---- weighted partial: partial[chunk][d] = sum_n p_n * X[n,d] ----
    // Thread t owns d = 2t..2t+1 (float2, coalesced). X chunk hot in L2/L3.
    {
        const float* xw = X + row0 * Dn + tid * 2;
        float2 a0 = make_float2(0.f, 0.f);
        float2 a1 = make_float2(0.f, 0.f);
#pragma unroll 4
        for (int n = 0; n < 128; n += 2) {
            float p0 = sc[n];
            float p1 = sc[n + 1];
            float2 x0 = *(const float2*)(xw + (long)n * Dn);
            float2 x1 = *(const float2*)(xw + (long)(n + 1) * Dn);
            a0.x += p0 * x0.x; a0.y += p0 * x0.y;
            a1.x += p1 * x1.x; a1.y += p1 * x1.y;
        }
        float2 r = make_float2(a0.x + a1.x, a0.y + a1.y);
        *(float2*)(partial + (long)blockIdx.x * Dn + tid * 2) = r;
    }
}

// ---------------- combine: out[b,d] = sum_c e^{m_c-M} partial[c][d] / L ------
// chunk c global = b*64 + c (64 chunks of 128 rows per batch)
__global__ __launch_bounds__(1024) void k_combine(const float* __restrict__ partial,
                                                  const float2* __restrict__ ml,
                                                  float* __restrict__ out) {
    const int b   = blockIdx.x;
    const int tid = threadIdx.x;
    __shared__ float ms[64];
    __shared__ float ls[64];
    __shared__ float es[64];

    if (tid < 64) {
        float2 v = ml[b * 64 + tid];
        ms[tid] = v.x;
        ls[tid] = v.y;
    }
    __syncthreads();

    float M = -1e30f;
#pragma unroll
    for (int c = 0; c < 64; ++c) M = fmaxf(M, ms[c]);   // uniform LDS broadcast
    if (tid < 64) es[tid] = __expf(ms[tid] - M);
    __syncthreads();

    float L = 0.f;
#pragma unroll
    for (int c = 0; c < 64; ++c) L += es[c] * ls[c];

    const float* p = partial + (long)b * 64 * Dn + tid;
    float acc = 0.f;
#pragma unroll 8
    for (int c = 0; c < 64; ++c) acc += es[c] * p[(long)c * Dn];

    out[b * Dn + tid] = acc / L;
}

extern "C" void kernel_launch(void* const* d_in, const int* in_sizes, int n_in,
                              void* d_out, int out_size, void* d_ws, size_t ws_size,
                              hipStream_t stream) {
    (void)in_sizes; (void)n_in; (void)ws_size; (void)out_size;
    const float* X  = (const float*)d_in[0];
    const float* W1 = (const float*)d_in[1];
    const float* W2 = (const float*)d_in[2];
    float* out = (float*)d_out;

    char* ws = (char*)d_ws;
    short*  w1s     = (short*)ws;                    // 512 KB (swizzled panels)
    float2* ml      = (float2*)(ws + (1 << 19));     // 8 KB  (m_c, l_c per chunk)
    float*  partial = (float*)(ws + (1 << 20));      // 4 MB  [1024 chunks][1024 d]

    k_cvt_w1<<<(Hn * Dn) / 8 / 256, 256, 0, stream>>>(W1, w1s);
    k_scores<<<(Bn * Nn) / 128, 512, 0, stream>>>(X, w1s, W2, ml, partial);
    k_combine<<<Bn, 1024, 0, stream>>>(partial, ml, out);
}